// Round 4
// baseline (166.388 us; speedup 1.0000x reference)
//
#include <hip/hip_runtime.h>

#define NFEAT 64
#define BSHIFT 8
#define BCOLS 256              // cols/rows per bucket = 1<<BSHIFT
#define NBMAX 512              // array size >= nbuck = ceil(100000/256) = 391
#define CAP 5120               // per-bucket capacity (mean 4092 + 16 sigma)
#define CHUNK 4096             // edges per partition block
#define PT 512                 // partition threads
#define NITP (CHUNK / PT)      // 8 reg-cached entries per thread
#define FT 512                 // fill threads
#define UT 512                 // fuse threads (8 waves)
#define FBIT (CAP / UT)        // 10 reg-cached entries per fuse thread

// ---------------------------------------------------------------------------
// out[c,f] = dinv[c]^2 x[c,f] + dinv[c] * sum_{e: col==c} dinv[row_e] x[row_e,f]
// dinv[i] = rsqrt(1 + deg_row[i])
//
// r1/r2/r3 lesson: LDS atomics (int AND f32) retire ~4 cyc per LANE at the
// single DS unit per CU. 7 per-edge atomics = ~73us of the 140us runtime.
// This round: wave-ballot ranking replaces ALL per-edge LDS atomics with
// per-wave count/cursor rows (cw[wave][bin]) + plain leader RMW:
//   mask  = AND over key bits of (bit ? ballot : ~ballot)  (valid-lanes only)
//   rank  = popc(mask & lower_lanes); leader = (rank==0); cnt = popc(mask)
//   count: leader does cw[wid][key] += cnt         (plain LDS, no race)
//   scatter: slot = cw[wid][key] + rank; leader bumps cursor
// Global per-BUCKET cursor atomics (<=512/block) remain — they're cheap.
// ---------------------------------------------------------------------------

__device__ __forceinline__ unsigned short f2bf(float f) {
    unsigned int u = __float_as_uint(f);
    return (unsigned short)((u + 0x7FFFu + ((u >> 16) & 1u)) >> 16);  // RNE
}

__device__ __forceinline__ float bflo(unsigned int u) {
    return __uint_as_float(u << 16);
}
__device__ __forceinline__ float bfhi(unsigned int u) {
    return __uint_as_float(u & 0xFFFF0000u);
}

template <int NB>
__device__ __forceinline__ unsigned long long eqmask(int key,
                                                     unsigned long long act) {
    unsigned long long m = act;
    #pragma unroll
    for (int b = 0; b < NB; b++) {
        unsigned long long bb = __ballot((key >> b) & 1);
        m &= ((key >> b) & 1) ? bb : ~bb;
    }
    return m;
}

__device__ __forceinline__ int wave_incl_scan(int v, int lane) {
    #pragma unroll
    for (int off = 1; off < 64; off <<= 1) {
        int u = __shfl_up(v, off);
        if (lane >= off) v += u;
    }
    return v;
}

__global__ void k_init(int* __restrict__ bcur, int* __restrict__ bcurR) {
    int t = threadIdx.x;           // NBMAX
    bcur[t]  = t * CAP;
    bcurR[t] = t * CAP;
}

// fused dual partition: col-buckets (int entries) + row-buckets (uchar),
// ballot-ranked (zero per-edge LDS atomics).
__global__ __launch_bounds__(PT)
void k_partCR(const int* __restrict__ rows, const int* __restrict__ cols,
              int* __restrict__ bcur, int* __restrict__ bcurR,
              int* __restrict__ part, unsigned char* __restrict__ partR, int E) {
    __shared__ int cwC[8][NBMAX];          // 16KB: per-wave counts -> cursors
    __shared__ int cwR[8][NBMAX];          // 16KB
    __shared__ int gbaseC[NBMAX];          // 2KB
    __shared__ int gbaseR[NBMAX];          // 2KB
    __shared__ int wsumC[8];
    __shared__ int wsumR[8];
    __shared__ int stageC[CHUNK];          // 16KB
    __shared__ unsigned char stageR[CHUNK];// 4KB
    __shared__ unsigned short bidC[CHUNK]; // 8KB
    __shared__ unsigned short bidR[CHUNK]; // 8KB
    int chunk0 = blockIdx.x * CHUNK;
    int cnt = min(CHUNK, E - chunk0);
    int t = threadIdx.x;           // PT = 512
    int lane = t & 63, wid = t >> 6;
    unsigned long long lowm = (1ULL << lane) - 1ULL;

    for (int i = t; i < 8 * NBMAX; i += PT) ((int*)cwC)[i] = 0;
    for (int i = t; i < 8 * NBMAX; i += PT) ((int*)cwR)[i] = 0;
    __syncthreads();

    // ---- count phase: load + ballot-group, leader accumulates ----
    int pk[NITP], cb[NITP];
    unsigned long long mC[NITP], mR[NITP];
    #pragma unroll
    for (int k = 0; k < NITP; k++) {
        int i = t + k * PT;
        bool valid = i < cnt;
        int c = 0, r = 0;
        if (valid) { c = cols[chunk0 + i]; r = rows[chunk0 + i]; }
        int b  = c >> BSHIFT;                      // 0..390 (9 bits)
        int b2 = r >> BSHIFT;
        pk[k] = ((c & (BCOLS - 1)) << 17) | r;     // col-low | row (rb,rpk derivable)
        cb[k] = b;
        unsigned long long act = __ballot(valid);
        unsigned long long mc = eqmask<9>(b, act);
        unsigned long long mr = eqmask<9>(b2, act);
        mC[k] = mc; mR[k] = mr;
        if (valid) {
            if (__popcll(mc & lowm) == 0) cwC[wid][b]  += __popcll(mc);
            if (__popcll(mr & lowm) == 0) cwR[wid][b2] += __popcll(mr);
        }
    }
    __syncthreads();

    // ---- totals, 512-bin scan, global cursor alloc, per-wave bases ----
    int v1 = 0, v2 = 0;
    #pragma unroll
    for (int w = 0; w < 8; w++) { v1 += cwC[w][t]; v2 += cwR[w][t]; }
    int inc1 = wave_incl_scan(v1, lane);
    if (lane == 63) wsumC[wid] = inc1;
    int inc2 = wave_incl_scan(v2, lane);
    if (lane == 63) wsumR[wid] = inc2;
    __syncthreads();
    int addC = 0, addR = 0;
    #pragma unroll
    for (int k = 0; k < 8; k++) {
        if (k < wid) { addC += wsumC[k]; addR += wsumR[k]; }
    }
    int exC = inc1 - v1 + addC;
    int exR = inc2 - v2 + addR;
    gbaseC[t] = (v1 > 0) ? (atomicAdd(&bcur[t], v1) - exC) : 0;
    gbaseR[t] = (v2 > 0) ? (atomicAdd(&bcurR[t], v2) - exR) : 0;
    int run = exC;
    #pragma unroll
    for (int w = 0; w < 8; w++) { int tmp = cwC[w][t]; cwC[w][t] = run; run += tmp; }
    run = exR;
    #pragma unroll
    for (int w = 0; w < 8; w++) { int tmp = cwR[w][t]; cwR[w][t] = run; run += tmp; }
    __syncthreads();

    // ---- scatter phase: cursor = per-wave base, leader bumps ----
    #pragma unroll
    for (int k = 0; k < NITP; k++) {
        int i = t + k * PT;
        bool valid = i < cnt;
        unsigned long long mc = mC[k], mr = mR[k];
        if (valid) {
            int b = cb[k];
            int rkC = __popcll(mc & lowm);
            int curC = cwC[wid][b];
            int p = curC + rkC;
            stageC[p] = pk[k];
            bidC[p] = (unsigned short)b;
            if (rkC == 0) cwC[wid][b] = curC + __popcll(mc);
            int b2 = (pk[k] >> 8) & 511;           // row>>8
            int rkR = __popcll(mr & lowm);
            int curR = cwR[wid][b2];
            int p2 = curR + rkR;
            stageR[p2] = (unsigned char)(pk[k] & 255);  // row&255
            bidR[p2] = (unsigned short)b2;
            if (rkR == 0) cwR[wid][b2] = curR + __popcll(mr);
        }
    }
    __syncthreads();

    // ---- coalesced global write ----
    for (int p = t; p < cnt; p += PT) {
        int b = bidC[p];
        int idx = gbaseC[b] + p;
        if (idx < (b + 1) * CAP) part[idx] = stageC[p];      // overflow clamp
        int b2 = bidR[p];
        int idx2 = gbaseR[b2] + p;
        if (idx2 < (b2 + 1) * CAP) partR[idx2] = stageR[p];
    }
}

// per bucket: ballot-count row occurrences -> dinv + xs = bf16(dinv*x)
__global__ __launch_bounds__(FT)
void k_fillR(const unsigned char* __restrict__ partR, const int* __restrict__ bcurR,
             const float4* __restrict__ x4, float* __restrict__ dinv,
             ushort4* __restrict__ xs4, int n) {
    __shared__ int cw[8][BCOLS];       // 8KB per-wave counts
    __shared__ float ldinv[BCOLS];
    int b = blockIdx.x;
    int s = b * CAP;
    int t = threadIdx.x;           // FT = 512
    int lane = t & 63, wid = t >> 6;
    unsigned long long lowm = (1ULL << lane) - 1ULL;

    int cntR = min(bcurR[b] - s, CAP);
    for (int i = t; i < 8 * BCOLS; i += FT) ((int*)cw)[i] = 0;
    __syncthreads();
    for (int base = 0; base < cntR; base += FT) {
        int i = base + t;
        bool valid = i < cntR;
        int key = 0;
        if (valid) key = partR[s + i];
        unsigned long long act = __ballot(valid);
        unsigned long long m = eqmask<8>(key, act);
        if (valid && __popcll(m & lowm) == 0) cw[wid][key] += __popcll(m);
    }
    __syncthreads();
    if (t < BCOLS) {
        int d = 0;
        #pragma unroll
        for (int w = 0; w < 8; w++) d += cw[w][t];
        float di = rsqrtf((float)(d + 1));           // +1 self loop
        ldinv[t] = di;
        int gr = (b << BSHIFT) + t;
        if (gr < n) dinv[gr] = di;
    }
    __syncthreads();
    size_t base4 = (size_t)(b << BSHIFT) << 4;       // float4 index of row b*256
    int lim = min(BCOLS, n - (b << BSHIFT)) << 4;
    for (int i = t; i < lim; i += FT) {
        float dd = ldinv[i >> 4];
        float4 vv = x4[base4 + i];
        ushort4 o;
        o.x = f2bf(dd * vv.x); o.y = f2bf(dd * vv.y);
        o.z = f2bf(dd * vv.z); o.w = f2bf(dd * vv.w);
        xs4[base4 + i] = o;
    }
}

// per bucket: ballot-built CSR in LDS, then register-accumulate gather.
__global__ __launch_bounds__(UT)
void k_fuse(const int* __restrict__ part, const int* __restrict__ bcur,
            const unsigned short* __restrict__ xs,
            const float* __restrict__ dinv,
            float4* __restrict__ out4, int n) {
    __shared__ int cw[8][BCOLS];       // 8KB per-wave counts -> cursors
    __shared__ int lcnt[BCOLS];
    __shared__ int lps[BCOLS];
    __shared__ int wsum[4];
    __shared__ int stage[CAP];         // 20KB
    int b = blockIdx.x;
    int s = b * CAP;
    int cnt = min(bcur[b] - s, CAP);
    int t = threadIdx.x;           // UT = 512
    int lane = t & 63, wid = t >> 6;
    unsigned long long lowm = (1ULL << lane) - 1ULL;

    for (int i = t; i < 8 * BCOLS; i += UT) ((int*)cw)[i] = 0;
    __syncthreads();

    // ---- count (ballot; masks recomputed in scatter to stay low-VGPR) ----
    int pk[FBIT];
    #pragma unroll
    for (int k = 0; k < FBIT; k++) {
        int i = t + k * UT;
        bool valid = i < cnt;
        int v2 = 0;
        if (valid) v2 = part[s + i];
        pk[k] = v2;
        int c = v2 >> 17;
        unsigned long long act = __ballot(valid);
        unsigned long long m = eqmask<8>(c, act);
        if (valid && __popcll(m & lowm) == 0) cw[wid][c] += __popcll(m);
    }
    __syncthreads();

    // ---- totals + 256-bin scan + per-wave bases ----
    int v = 0, inc = 0;
    if (t < BCOLS) {
        #pragma unroll
        for (int w = 0; w < 8; w++) v += cw[w][t];
        inc = wave_incl_scan(v, lane);
        if (lane == 63) wsum[wid] = inc;
    }
    __syncthreads();
    if (t < BCOLS) {
        int add = 0;
        if (wid > 0) add += wsum[0];
        if (wid > 1) add += wsum[1];
        if (wid > 2) add += wsum[2];
        int ex = inc - v + add;
        lps[t] = ex;
        lcnt[t] = v;
        int run = ex;
        #pragma unroll
        for (int w = 0; w < 8; w++) { int tmp = cw[w][t]; cw[w][t] = run; run += tmp; }
    }
    __syncthreads();

    // ---- scatter ----
    #pragma unroll
    for (int k = 0; k < FBIT; k++) {
        int i = t + k * UT;
        bool valid = i < cnt;
        int v2 = pk[k];
        int c = v2 >> 17;
        unsigned long long act = __ballot(valid);
        unsigned long long m = eqmask<8>(c, act);
        if (valid) {
            int rk = __popcll(m & lowm);
            int cur = cw[wid][c];
            stage[cur + rk] = v2 & 0x1FFFF;          // pure row id
            if (rk == 0) cw[wid][c] = cur + __popcll(m);
        }
    }
    __syncthreads();

    // ---- gather: 64 groups x 8 lanes; each group owns 4 cols ----
    int gg = t >> 3, li = t & 7;
    #pragma unroll
    for (int cc = 0; cc < BCOLS; cc += 64) {
        int c = cc + gg;
        int node = (b << BSHIFT) + c;
        if (node < n) {
            int ss = lps[c];
            int len = lcnt[c];
            float a0 = 0.f, a1 = 0.f, a2 = 0.f, a3 = 0.f;
            float a4 = 0.f, a5 = 0.f, a6 = 0.f, a7 = 0.f;
            int npair = len >> 1;
            uint4 u0, u1;
            if (npair > 0) {
                int r0 = stage[ss], r1 = stage[ss + 1];
                u0 = *((const uint4*)(xs + ((size_t)r0 << 6)) + li);
                u1 = *((const uint4*)(xs + ((size_t)r1 << 6)) + li);
            }
            for (int q = 1; q < npair; q++) {
                int p = ss + q * 2;
                int r0 = stage[p], r1 = stage[p + 1];
                uint4 n0 = *((const uint4*)(xs + ((size_t)r0 << 6)) + li);
                uint4 n1 = *((const uint4*)(xs + ((size_t)r1 << 6)) + li);
                a0 += bflo(u0.x); a1 += bfhi(u0.x);
                a2 += bflo(u0.y); a3 += bfhi(u0.y);
                a4 += bflo(u0.z); a5 += bfhi(u0.z);
                a6 += bflo(u0.w); a7 += bfhi(u0.w);
                a0 += bflo(u1.x); a1 += bfhi(u1.x);
                a2 += bflo(u1.y); a3 += bfhi(u1.y);
                a4 += bflo(u1.z); a5 += bfhi(u1.z);
                a6 += bflo(u1.w); a7 += bfhi(u1.w);
                u0 = n0; u1 = n1;
            }
            if (npair > 0) {
                a0 += bflo(u0.x); a1 += bfhi(u0.x);
                a2 += bflo(u0.y); a3 += bfhi(u0.y);
                a4 += bflo(u0.z); a5 += bfhi(u0.z);
                a6 += bflo(u0.w); a7 += bfhi(u0.w);
                a0 += bflo(u1.x); a1 += bfhi(u1.x);
                a2 += bflo(u1.y); a3 += bfhi(u1.y);
                a4 += bflo(u1.z); a5 += bfhi(u1.z);
                a6 += bflo(u1.w); a7 += bfhi(u1.w);
            }
            if (len & 1) {
                int r = stage[ss + len - 1];
                uint4 u = *((const uint4*)(xs + ((size_t)r << 6)) + li);
                a0 += bflo(u.x); a1 += bfhi(u.x);
                a2 += bflo(u.y); a3 += bfhi(u.y);
                a4 += bflo(u.z); a5 += bfhi(u.z);
                a6 += bflo(u.w); a7 += bfhi(u.w);
            }
            // self term + scale + store
            float dc = dinv[node];
            uint4 us = *((const uint4*)(xs + ((size_t)node << 6)) + li);
            float4 r0o, r1o;
            r0o.x = dc * (a0 + bflo(us.x));
            r0o.y = dc * (a1 + bfhi(us.x));
            r0o.z = dc * (a2 + bflo(us.y));
            r0o.w = dc * (a3 + bfhi(us.y));
            r1o.x = dc * (a4 + bflo(us.z));
            r1o.y = dc * (a5 + bfhi(us.z));
            r1o.z = dc * (a6 + bflo(us.w));
            r1o.w = dc * (a7 + bfhi(us.w));
            size_t ob = ((size_t)node << 4) + (li << 1);
            out4[ob] = r0o;
            out4[ob + 1] = r1o;
        }
    }
}

extern "C" void kernel_launch(void* const* d_in, const int* in_sizes, int n_in,
                              void* d_out, int out_size, void* d_ws, size_t ws_size,
                              hipStream_t stream) {
    const float* x    = (const float*)d_in[0];
    const int*   eidx = (const int*)d_in[1];   // int32 (JAX x64 disabled)

    const int n = in_sizes[0] / NFEAT;         // 100000
    const int E = in_sizes[1] / 2;             // 1600000
    const int* rows = eidx;
    const int* cols = eidx + E;
    float* out = (float*)d_out;

    const int nbuck = (n + BCOLS - 1) >> BSHIFT;   // 391

    // ws: bcur[NBMAX] | bcurR[NBMAX] | dinv[n]
    //     | xs[n*64 bf16, 16B-aligned] | part[nbuck*CAP ints] | partR[uchar]
    char* w = (char*)d_ws;
    int*   bcur  = (int*)w;     w += NBMAX * 4;
    int*   bcurR = (int*)w;     w += NBMAX * 4;
    float* dinv  = (float*)w;   w += (size_t)n * 4;
    w = (char*)(((uintptr_t)w + 15) & ~(uintptr_t)15);
    unsigned short* xs = (unsigned short*)w;  w += (size_t)n * NFEAT * 2;
    int*   part  = (int*)w;     w += (size_t)nbuck * CAP * 4;
    unsigned char* partR = (unsigned char*)w;

    k_init<<<1, NBMAX, 0, stream>>>(bcur, bcurR);

    int nchunk = (E + CHUNK - 1) / CHUNK;      // 391
    k_partCR<<<nchunk, PT, 0, stream>>>(rows, cols, bcur, bcurR, part, partR, E);
    k_fillR<<<nbuck, FT, 0, stream>>>(partR, bcurR, (const float4*)x,
                                      dinv, (ushort4*)xs, n);
    k_fuse<<<nbuck, UT, 0, stream>>>(part, bcur, xs, dinv,
                                     (float4*)out, n);
}

// Round 5
// 143.090 us; speedup vs baseline: 1.1628x; 1.1628x over previous
//
#include <hip/hip_runtime.h>

#define NFEAT 64
#define BSHIFT 8
#define BCOLS 256              // cols/rows per bucket = 1<<BSHIFT
#define NBMAX 512              // array size >= nbuck = ceil(100000/256) = 391
#define CAP 5120               // per-bucket capacity (mean 4092 + 16 sigma)
#define CHUNK 3136             // edges per partition block (-> ~2 blocks/CU)
#define PT 512                 // partition threads
#define NITP 7                 // ceil(CHUNK / PT) reg-cached entries per thread
#define FT 512                 // fill threads
#define UT 512                 // fuse threads (8 waves)
#define FBIT (CAP / UT)        // 10 reg-cached entries per fuse scan thread
#define QCAP 1664              // per-quarter stage capacity (mean 1024 + 20 sigma)

// ---------------------------------------------------------------------------
// out[c,f] = dinv[c]^2 x[c,f] + dinv[c] * sum_{e: col==c} dinv[row_e] x[row_e,f]
// dinv[i] = rsqrt(1 + deg_row[i])
//
// r1/r2 lesson: LDS atomics (int and f32) retire ~4 cyc per LANE at the DS
// unit. r4 lesson: ballot-ranking is WORSE (eqmask VALU chains + divergent
// leader RMW). The atomic algorithm stands; this round fixes BALANCE +
// OVERLAP: 391-block grids left half the CUs with 1 block (no cross-block
// DS/memory phase overlap, makespan 1.31x). Now:
//   k_partCR : 511 blocks (CHUNK=3136) ~= exactly 2/CU
//   k_fillR  : 782 half-bucket blocks (128 rows each)
//   k_fuse   : 1564 quarter-bucket blocks (64 cols each): scan bucket list
//              once (reg-cached), CSR only for own quarter, gather with one
//              col per 8-lane group. DS phases of one block overlap memory
//              phases of its CU-neighbors.
// ---------------------------------------------------------------------------

__device__ __forceinline__ unsigned short f2bf(float f) {
    unsigned int u = __float_as_uint(f);
    return (unsigned short)((u + 0x7FFFu + ((u >> 16) & 1u)) >> 16);  // RNE
}

__device__ __forceinline__ float bflo(unsigned int u) {
    return __uint_as_float(u << 16);
}
__device__ __forceinline__ float bfhi(unsigned int u) {
    return __uint_as_float(u & 0xFFFF0000u);
}

__device__ __forceinline__ int wave_incl_scan(int v, int lane) {
    #pragma unroll
    for (int off = 1; off < 64; off <<= 1) {
        int u = __shfl_up(v, off);
        if (lane >= off) v += u;
    }
    return v;
}

__global__ void k_init(int* __restrict__ bcur, int* __restrict__ bcurR) {
    int t = threadIdx.x;           // NBMAX
    bcur[t]  = t * CAP;
    bcurR[t] = t * CAP;
}

// fused dual partition: col-buckets (int entries) + row-buckets (uchar)
__global__ __launch_bounds__(PT)
void k_partCR(const int* __restrict__ rows, const int* __restrict__ cols,
              int* __restrict__ bcur, int* __restrict__ bcurR,
              int* __restrict__ part, unsigned char* __restrict__ partR, int E) {
    __shared__ int histC[NBMAX];
    __shared__ int histR[NBMAX];
    __shared__ int gbaseC[NBMAX];
    __shared__ int gbaseR[NBMAX];
    __shared__ int wsumC[8];
    __shared__ int wsumR[8];
    __shared__ int stageC[CHUNK];
    __shared__ unsigned char stageR[CHUNK];
    __shared__ unsigned short bidC[CHUNK];
    __shared__ unsigned short bidR[CHUNK];
    int chunk0 = blockIdx.x * CHUNK;
    int cnt = min(CHUNK, E - chunk0);
    int t = threadIdx.x;           // PT = 512
    int lane = t & 63, wid = t >> 6;

    histC[t] = 0; histR[t] = 0;
    __syncthreads();

    int pk[NITP];
    unsigned char rpk[NITP];
    unsigned short cb[NITP], rb[NITP];
    #pragma unroll
    for (int k = 0; k < NITP; k++) {
        int i = t + k * PT;
        if (i < cnt) {
            int c = cols[chunk0 + i];
            int r = rows[chunk0 + i];
            int b  = c >> BSHIFT;
            int b2 = r >> BSHIFT;
            pk[k]  = ((c & (BCOLS - 1)) << 17) | r;
            rpk[k] = (unsigned char)(r & (BCOLS - 1));
            cb[k] = (unsigned short)b;
            rb[k] = (unsigned short)b2;
            atomicAdd(&histC[b], 1);
            atomicAdd(&histR[b2], 1);
        }
    }
    __syncthreads();

    // two 512-bin scans (all 8 waves each), separate wsum arrays, one barrier
    int v1 = histC[t];
    int inc1 = wave_incl_scan(v1, lane);
    if (lane == 63) wsumC[wid] = inc1;
    int v2 = histR[t];
    int inc2 = wave_incl_scan(v2, lane);
    if (lane == 63) wsumR[wid] = inc2;
    __syncthreads();
    int addC = 0, addR = 0;
    #pragma unroll
    for (int k = 0; k < 8; k++) {
        if (k < wid) { addC += wsumC[k]; addR += wsumR[k]; }
    }
    int exC = inc1 - v1 + addC;
    int exR = inc2 - v2 + addR;
    gbaseC[t] = (v1 > 0) ? (atomicAdd(&bcur[t], v1) - exC) : 0;
    gbaseR[t] = (v2 > 0) ? (atomicAdd(&bcurR[t], v2) - exR) : 0;
    histC[t] = exC;                // becomes cursor
    histR[t] = exR;
    __syncthreads();

    #pragma unroll
    for (int k = 0; k < NITP; k++) {
        int i = t + k * PT;
        if (i < cnt) {
            int p = atomicAdd(&histC[cb[k]], 1);
            stageC[p] = pk[k];
            bidC[p] = cb[k];
            int p2 = atomicAdd(&histR[rb[k]], 1);
            stageR[p2] = rpk[k];
            bidR[p2] = rb[k];
        }
    }
    __syncthreads();
    for (int p = t; p < cnt; p += PT) {
        int b = bidC[p];
        int idx = gbaseC[b] + p;
        if (idx < (b + 1) * CAP) part[idx] = stageC[p];      // overflow clamp
        int b2 = bidR[p];
        int idx2 = gbaseR[b2] + p;
        if (idx2 < (b2 + 1) * CAP) partR[idx2] = stageR[p];
    }
}

// per HALF-bucket (128 rows): count partR -> dinv + xs = bf16(dinv*x)
__global__ __launch_bounds__(FT)
void k_fillR(const unsigned char* __restrict__ partR, const int* __restrict__ bcurR,
             const float4* __restrict__ x4, float* __restrict__ dinv,
             ushort4* __restrict__ xs4, int n) {
    __shared__ int lcnt[128];
    __shared__ float ldinv[128];
    int bh = blockIdx.x;
    int b = bh >> 1, half = bh & 1;
    int s = b * CAP;
    int t = threadIdx.x;           // FT = 512

    int cntR = min(bcurR[b] - s, CAP);
    if (t < 128) lcnt[t] = 0;
    __syncthreads();
    for (int i = t; i < cntR; i += FT) {
        int key = partR[s + i];
        if ((key >> 7) == half) atomicAdd(&lcnt[key & 127], 1);
    }
    __syncthreads();
    int rows_base = (b << BSHIFT) + (half << 7);
    if (t < 128) {
        float d = rsqrtf((float)(lcnt[t] + 1));      // +1 self loop
        ldinv[t] = d;
        int gr = rows_base + t;
        if (gr < n) dinv[gr] = d;
    }
    __syncthreads();
    size_t base4 = (size_t)rows_base << 4;           // float4 index of first row
    int nr = n - rows_base;
    if (nr <= 0) return;
    int lim = min(128, nr) << 4;
    for (int i = t; i < lim; i += FT) {
        float dd = ldinv[i >> 4];
        float4 vv = x4[base4 + i];
        ushort4 o;
        o.x = f2bf(dd * vv.x); o.y = f2bf(dd * vv.y);
        o.z = f2bf(dd * vv.z); o.w = f2bf(dd * vv.w);
        xs4[base4 + i] = o;
    }
}

// per QUARTER-bucket (64 cols): scan bucket list (reg-cached), CSR for own
// quarter only, then gather: one col per 8-lane group.
__global__ __launch_bounds__(UT)
void k_fuse(const int* __restrict__ part, const int* __restrict__ bcur,
            const unsigned short* __restrict__ xs,
            const float* __restrict__ dinv,
            float4* __restrict__ out4, int n) {
    __shared__ int lcnt[64];
    __shared__ int lps[64];
    __shared__ int cur[64];
    __shared__ int stage[QCAP];        // 6.5KB
    int qb = blockIdx.x;
    int b = qb >> 2, q = qb & 3;
    int s = b * CAP;
    int cnt = min(bcur[b] - s, CAP);
    int t = threadIdx.x;           // UT = 512

    if (t < 64) lcnt[t] = 0;
    __syncthreads();

    // ---- scan + count own quarter ----
    int pk[FBIT];
    #pragma unroll
    for (int k = 0; k < FBIT; k++) {
        int i = t + k * UT;
        int v2 = (i < cnt) ? part[s + i] : -1;
        pk[k] = v2;
        if (v2 >= 0) {
            int c = v2 >> 17;              // 0..255 col-low
            if ((c >> 6) == q) atomicAdd(&lcnt[c & 63], 1);
        }
    }
    __syncthreads();

    // ---- 64-bin scan by wave 0 ----
    if (t < 64) {
        int v = lcnt[t];
        int inc = wave_incl_scan(v, t);
        int ex = inc - v;
        lps[t] = ex;
        cur[t] = ex;
    }
    __syncthreads();

    // ---- scatter own quarter ----
    #pragma unroll
    for (int k = 0; k < FBIT; k++) {
        int v2 = pk[k];
        if (v2 >= 0) {
            int c = v2 >> 17;
            if ((c >> 6) == q) {
                int p = atomicAdd(&cur[c & 63], 1);
                if (p < QCAP) stage[p] = v2 & 0x1FFFF;   // pure row id
            }
        }
    }
    __syncthreads();

    // ---- gather: 64 groups x 8 lanes; group g owns col q*64+g ----
    int g = t >> 3, li = t & 7;
    int node = (b << BSHIFT) + (q << 6) + g;
    if (node >= n) return;
    int ss = lps[g];
    int len = lcnt[g];
    if (ss + len > QCAP) len = QCAP > ss ? QCAP - ss : 0;   // overflow clamp
    float a0 = 0.f, a1 = 0.f, a2 = 0.f, a3 = 0.f;
    float a4 = 0.f, a5 = 0.f, a6 = 0.f, a7 = 0.f;
    int npair = len >> 1;
    uint4 u0, u1;
    if (npair > 0) {
        int r0 = stage[ss], r1 = stage[ss + 1];
        u0 = *((const uint4*)(xs + ((size_t)r0 << 6)) + li);
        u1 = *((const uint4*)(xs + ((size_t)r1 << 6)) + li);
    }
    for (int qq = 1; qq < npair; qq++) {
        int p = ss + qq * 2;
        int r0 = stage[p], r1 = stage[p + 1];
        uint4 n0 = *((const uint4*)(xs + ((size_t)r0 << 6)) + li);
        uint4 n1 = *((const uint4*)(xs + ((size_t)r1 << 6)) + li);
        a0 += bflo(u0.x); a1 += bfhi(u0.x);
        a2 += bflo(u0.y); a3 += bfhi(u0.y);
        a4 += bflo(u0.z); a5 += bfhi(u0.z);
        a6 += bflo(u0.w); a7 += bfhi(u0.w);
        a0 += bflo(u1.x); a1 += bfhi(u1.x);
        a2 += bflo(u1.y); a3 += bfhi(u1.y);
        a4 += bflo(u1.z); a5 += bfhi(u1.z);
        a6 += bflo(u1.w); a7 += bfhi(u1.w);
        u0 = n0; u1 = n1;
    }
    if (npair > 0) {
        a0 += bflo(u0.x); a1 += bfhi(u0.x);
        a2 += bflo(u0.y); a3 += bfhi(u0.y);
        a4 += bflo(u0.z); a5 += bfhi(u0.z);
        a6 += bflo(u0.w); a7 += bfhi(u0.w);
        a0 += bflo(u1.x); a1 += bfhi(u1.x);
        a2 += bflo(u1.y); a3 += bfhi(u1.y);
        a4 += bflo(u1.z); a5 += bfhi(u1.z);
        a6 += bflo(u1.w); a7 += bfhi(u1.w);
    }
    if (len & 1) {
        int r = stage[ss + len - 1];
        uint4 u = *((const uint4*)(xs + ((size_t)r << 6)) + li);
        a0 += bflo(u.x); a1 += bfhi(u.x);
        a2 += bflo(u.y); a3 += bfhi(u.y);
        a4 += bflo(u.z); a5 += bfhi(u.z);
        a6 += bflo(u.w); a7 += bfhi(u.w);
    }
    // self term + scale + store
    float dc = dinv[node];
    uint4 us = *((const uint4*)(xs + ((size_t)node << 6)) + li);
    float4 r0o, r1o;
    r0o.x = dc * (a0 + bflo(us.x));
    r0o.y = dc * (a1 + bfhi(us.x));
    r0o.z = dc * (a2 + bflo(us.y));
    r0o.w = dc * (a3 + bfhi(us.y));
    r1o.x = dc * (a4 + bflo(us.z));
    r1o.y = dc * (a5 + bfhi(us.z));
    r1o.z = dc * (a6 + bflo(us.w));
    r1o.w = dc * (a7 + bfhi(us.w));
    size_t ob = ((size_t)node << 4) + (li << 1);
    out4[ob] = r0o;
    out4[ob + 1] = r1o;
}

extern "C" void kernel_launch(void* const* d_in, const int* in_sizes, int n_in,
                              void* d_out, int out_size, void* d_ws, size_t ws_size,
                              hipStream_t stream) {
    const float* x    = (const float*)d_in[0];
    const int*   eidx = (const int*)d_in[1];   // int32 (JAX x64 disabled)

    const int n = in_sizes[0] / NFEAT;         // 100000
    const int E = in_sizes[1] / 2;             // 1600000
    const int* rows = eidx;
    const int* cols = eidx + E;
    float* out = (float*)d_out;

    const int nbuck = (n + BCOLS - 1) >> BSHIFT;   // 391

    // ws: bcur[NBMAX] | bcurR[NBMAX] | dinv[n]
    //     | xs[n*64 bf16, 16B-aligned] | part[nbuck*CAP ints] | partR[uchar]
    char* w = (char*)d_ws;
    int*   bcur  = (int*)w;     w += NBMAX * 4;
    int*   bcurR = (int*)w;     w += NBMAX * 4;
    float* dinv  = (float*)w;   w += (size_t)n * 4;
    w = (char*)(((uintptr_t)w + 15) & ~(uintptr_t)15);
    unsigned short* xs = (unsigned short*)w;  w += (size_t)n * NFEAT * 2;
    int*   part  = (int*)w;     w += (size_t)nbuck * CAP * 4;
    unsigned char* partR = (unsigned char*)w;

    k_init<<<1, NBMAX, 0, stream>>>(bcur, bcurR);

    int nchunk = (E + CHUNK - 1) / CHUNK;      // 511  (~2 blocks/CU exactly)
    k_partCR<<<nchunk, PT, 0, stream>>>(rows, cols, bcur, bcurR, part, partR, E);
    k_fillR<<<nbuck * 2, FT, 0, stream>>>(partR, bcurR, (const float4*)x,
                                          dinv, (ushort4*)xs, n);
    k_fuse<<<nbuck * 4, UT, 0, stream>>>(part, bcur, xs, dinv,
                                         (float4*)out, n);
}